// Round 1
// baseline (803.473 us; speedup 1.0000x reference)
//
#include <hip/hip_runtime.h>
#include <cstdint>
#include <cstddef>

#define S_ 2048
#define B_ 4
#define H_ 16

typedef __attribute__((ext_vector_type(8))) __bf16 bf16x8;
typedef __attribute__((ext_vector_type(4))) float f32x4;

__device__ __forceinline__ f32x4 mfma16(bf16x8 a, bf16x8 b, f32x4 c) {
  return __builtin_amdgcn_mfma_f32_16x16x32_bf16(a, b, c, 0, 0, 0);
}

// async global->LDS, 16B per lane. LDS base must be wave-uniform (HW writes
// base + lane*16); global src is per-lane.
__device__ __forceinline__ void gll16(const void* g, void* l) {
  __builtin_amdgcn_global_load_lds(
      (__attribute__((address_space(1))) void*)(uintptr_t)g,
      (__attribute__((address_space(3))) void*)(uint32_t)(uintptr_t)l,
      16, 0, 0);
}

// ---------------- prep kernels ----------------

__global__ __launch_bounds__(256) void mla_cvt_x(const float* __restrict__ x,
                                                 __bf16* __restrict__ xb) {
  const size_t i = ((size_t)blockIdx.x * 256 + threadIdx.x) * 8;
  float4 a = *(const float4*)&x[i];
  float4 b = *(const float4*)&x[i + 4];
  bf16x8 v;
  v[0] = (__bf16)a.x; v[1] = (__bf16)a.y; v[2] = (__bf16)a.z; v[3] = (__bf16)a.w;
  v[4] = (__bf16)b.x; v[5] = (__bf16)b.y; v[6] = (__bf16)b.z; v[7] = (__bf16)b.w;
  *(bf16x8*)&xb[i] = v;
}

// W (K x N, f32, row-major) -> WT (N x K, bf16, row-major)
__global__ void mla_transpose(const float* __restrict__ W, __bf16* __restrict__ WT,
                              int K, int N) {
  __shared__ float tile[32][33];
  const int n0 = blockIdx.x * 32, k0 = blockIdx.y * 32;
  const int tx = threadIdx.x, ty = threadIdx.y;
#pragma unroll
  for (int i = 0; i < 32; i += 8)
    tile[ty + i][tx] = W[(size_t)(k0 + ty + i) * N + n0 + tx];
  __syncthreads();
#pragma unroll
  for (int i = 0; i < 32; i += 8)
    WT[(size_t)(n0 + ty + i) * K + k0 + tx] = (__bf16)tile[tx][ty + i];
}

__global__ void mla_bias(const float* __restrict__ b_dq, const float* __restrict__ b_dkv,
                         const float* __restrict__ b_kr, const float* __restrict__ b_uq,
                         const float* __restrict__ b_qr, const float* __restrict__ b_uk,
                         const float* __restrict__ b_uv, float* __restrict__ bias_d,
                         float* __restrict__ bias_uq, float* __restrict__ bias_ukv) {
  const int t = blockIdx.x * 256 + threadIdx.x;
  if (t < 384)
    bias_d[t] = (t < 128) ? b_dq[t] : (t < 256) ? b_dkv[t - 128]
               : (t < 288) ? b_kr[t - 256] : 0.f;
  if (t < 1536) bias_uq[t] = (t < 1024) ? b_uq[t] : b_qr[t - 1024];
  if (t < 2048) bias_ukv[t] = (t < 1024) ? b_uk[t] : b_uv[t - 1024];
}

__global__ void mla_rope_tab(float* __restrict__ c, float* __restrict__ sn) {
  const int t = blockIdx.x * 256 + threadIdx.x;  // t < S_*16
  const int s = t >> 4, i = t & 15;
  // 10000^(-i/16) = exp2(-i * log2(10000)/16)
  const float inv = exp2f(-(float)i * (13.287712379549449f / 16.0f));
  const float ang = (float)s * inv;
  c[t] = cosf(ang);
  sn[t] = sinf(ang);
}

// ---------------- bf16 MFMA GEMM: C = A(MxK) * BT^T + bias ----------------
// A row-major (lda), BT is B transposed: N x K row-major (ldbt).
// 128x128 tile, BK=32, 4 waves in 2x2, 16 mfma(16x16x32)/k-step.
template <bool OUTF32>
__global__ __launch_bounds__(256) void gemm_bf16k(
    const __bf16* __restrict__ A, int lda, const __bf16* __restrict__ BT, int ldbt,
    const float* __restrict__ bias, void* __restrict__ Cout, int ldc, int K) {
  const int n0 = blockIdx.x * 128;
  const int m0 = blockIdx.y * 128;
  const int tid = threadIdx.x;
  const int wave = tid >> 6, lane = tid & 63;
  const int g = lane >> 4, li = lane & 15;
  const int wm = (wave >> 1) * 64, wn = (wave & 1) * 64;
  __shared__ __bf16 __attribute__((aligned(16))) ldsA[128 * 32];
  __shared__ __bf16 __attribute__((aligned(16))) ldsB[128 * 32];

  const f32x4 fz = {0.f, 0.f, 0.f, 0.f};
  f32x4 acc[4][4];
#pragma unroll
  for (int i = 0; i < 4; ++i)
#pragma unroll
    for (int j = 0; j < 4; ++j) acc[i][j] = fz;

  const int srow = lane >> 2;        // 0..15 within chunk
  const int skc = (lane & 3) * 8;    // k sub-offset (elems)

  for (int k0 = 0; k0 < K; k0 += 32) {
    __syncthreads();  // previous iteration's LDS reads done
#pragma unroll
    for (int c = 0; c < 4; ++c) {
      const int chunk = wave * 4 + c;           // 0..15
      const int r8 = (chunk & 7) * 16 + srow;   // tile row (A: m, B: n)
      if (chunk < 8)
        gll16(&A[(size_t)(m0 + r8) * lda + k0 + skc], &ldsA[(chunk & 7) * 512]);
      else
        gll16(&BT[(size_t)(n0 + r8) * ldbt + k0 + skc], &ldsB[(chunk & 7) * 512]);
    }
    __syncthreads();  // drains vmcnt -> staged data visible

    bf16x8 af[4], bfv[4];
#pragma unroll
    for (int mi = 0; mi < 4; ++mi)
      af[mi] = *(const bf16x8*)&ldsA[(wm + mi * 16 + li) * 32 + g * 8];
#pragma unroll
    for (int ni = 0; ni < 4; ++ni)
      bfv[ni] = *(const bf16x8*)&ldsB[(wn + ni * 16 + li) * 32 + g * 8];
#pragma unroll
    for (int mi = 0; mi < 4; ++mi)
#pragma unroll
      for (int ni = 0; ni < 4; ++ni)
        acc[mi][ni] = mfma16(af[mi], bfv[ni], acc[mi][ni]);
  }

#pragma unroll
  for (int ni = 0; ni < 4; ++ni) {
    const int col = n0 + wn + ni * 16 + li;
    const float bv = bias[col];
#pragma unroll
    for (int mi = 0; mi < 4; ++mi) {
#pragma unroll
      for (int r = 0; r < 4; ++r) {
        const int row = m0 + wm + mi * 16 + 4 * g + r;
        const float v = acc[mi][ni][r] + bv;
        if (OUTF32)
          ((float*)Cout)[(size_t)row * ldc + col] = v;
        else
          ((__bf16*)Cout)[(size_t)row * ldc + col] = (__bf16)v;
      }
    }
  }
}

// ---------------- glue: build q_t / k_t with RoPE ----------------
__global__ __launch_bounds__(256) void mla_build_qk(
    const __bf16* __restrict__ qup, const __bf16* __restrict__ kvup,
    const __bf16* __restrict__ cqkvr, const float* __restrict__ ropec,
    const float* __restrict__ ropes, __bf16* __restrict__ qt,
    __bf16* __restrict__ ktb) {
  const int bs = blockIdx.x;   // b*S + s
  const int b = bs >> 11;
  const int s = bs & 2047;
  __shared__ float krr[32];
  if (threadIdx.x < 16) {
    const int i = threadIdx.x;
    const float r = (float)cqkvr[(size_t)bs * 384 + 256 + 2 * i];
    const float im = (float)cqkvr[(size_t)bs * 384 + 256 + 2 * i + 1];
    const float c = ropec[s * 16 + i], sn = ropes[s * 16 + i];
    krr[2 * i] = r * c - im * sn;
    krr[2 * i + 1] = r * sn + im * c;
  }
  __syncthreads();
  for (int idx = threadIdx.x; idx < 1536; idx += 256) {
    const int h = idx / 96, d = idx - h * 96;
    const size_t orow = ((size_t)(b * H_ + h) * S_ + s) * 96;
    float qv, kv;
    if (d < 64) {
      qv = (float)qup[(size_t)bs * 1536 + h * 64 + d];
      kv = (float)kvup[(size_t)bs * 2048 + h * 64 + d];
    } else {
      const int i = (d - 64) >> 1;
      const float c = ropec[s * 16 + i], sn = ropes[s * 16 + i];
      const float r = (float)qup[(size_t)bs * 1536 + 1024 + h * 32 + 2 * i];
      const float im = (float)qup[(size_t)bs * 1536 + 1024 + h * 32 + 2 * i + 1];
      qv = (((d - 64) & 1) == 0) ? (r * c - im * sn) : (r * sn + im * c);
      kv = krr[d - 64];
    }
    qt[orow + d] = (__bf16)qv;
    ktb[orow + d] = (__bf16)kv;
  }
}

// ---------------- glue: V -> V^T (B,H,64,S) ----------------
__global__ __launch_bounds__(256) void mla_vtrans(const __bf16* __restrict__ kvup,
                                                  __bf16* __restrict__ vt) {
  const int s0 = blockIdx.x * 64;
  const int bh = blockIdx.y;
  const int b = bh >> 4, h = bh & 15;
  __shared__ __bf16 __attribute__((aligned(16))) tile[64][72];
  const int t = threadIdx.x;
  {
    const int r = t >> 2, c0 = (t & 3) * 16;
    const size_t src = (size_t)(b * S_ + s0 + r) * 2048 + 1024 + h * 64 + c0;
    bf16x8 u0 = *(const bf16x8*)&kvup[src];
    bf16x8 u1 = *(const bf16x8*)&kvup[src + 8];
    *(bf16x8*)&tile[r][c0] = u0;
    *(bf16x8*)&tile[r][c0 + 8] = u1;
  }
  __syncthreads();
  {
    const int d = t >> 2, sc0 = (t & 3) * 16;
    bf16x8 w0, w1;
#pragma unroll
    for (int e = 0; e < 8; ++e) {
      w0[e] = tile[sc0 + e][d];
      w1[e] = tile[sc0 + 8 + e][d];
    }
    const size_t dst = ((size_t)bh * 64 + d) * S_ + s0 + sc0;
    *(bf16x8*)&vt[dst] = w0;
    *(bf16x8*)&vt[dst + 8] = w1;
  }
}

// ---------------- causal flash attention ----------------
// grid (S/64, B*H), 4 waves/block; wave owns 16 q-rows. KV tiles of 64.
__global__ __launch_bounds__(256) void mla_attn(const __bf16* __restrict__ qt,
                                                const __bf16* __restrict__ kt,
                                                const __bf16* __restrict__ vt,
                                                __bf16* __restrict__ ao) {
  const int qtile = blockIdx.x;
  const int bh = blockIdx.y;
  const int wave = threadIdx.x >> 6, lane = threadIdx.x & 63;
  const int g = lane >> 4, li = lane & 15;
  const int q0 = qtile * 64 + wave * 16;
  const float alpha = 1.4426950408889634f / sqrtf(96.0f);  // SCALE * log2(e)
  const __bf16* Q = qt + (size_t)bh * S_ * 96;
  const __bf16* Kp = kt + (size_t)bh * S_ * 96;
  const __bf16* Vp = vt + (size_t)bh * 64 * S_;
  __shared__ __bf16 __attribute__((aligned(16))) plds[4][16 * 64];

  bf16x8 qf[3];
#pragma unroll
  for (int kd = 0; kd < 3; ++kd)
    qf[kd] = *(const bf16x8*)&Q[(size_t)(q0 + li) * 96 + kd * 32 + g * 8];

  const f32x4 fz = {0.f, 0.f, 0.f, 0.f};
  f32x4 o[4];
  float m[4], L[4];
#pragma unroll
  for (int i = 0; i < 4; ++i) {
    o[i] = fz;
    m[i] = -3.0e38f;
    L[i] = 0.f;
  }

  for (int t = 0; t <= qtile; ++t) {
    const int kv0 = t * 64;
    f32x4 sf[4];
#pragma unroll
    for (int i = 0; i < 4; ++i) sf[i] = fz;
#pragma unroll
    for (int kq = 0; kq < 4; ++kq) {
      const __bf16* Kr = &Kp[(size_t)(kv0 + kq * 16 + li) * 96];
#pragma unroll
      for (int kd = 0; kd < 3; ++kd) {
        bf16x8 kf = *(const bf16x8*)&Kr[kd * 32 + g * 8];
        sf[kq] = mfma16(qf[kd], kf, sf[kq]);
      }
    }
    const bool maskt = (t == qtile);
#pragma unroll
    for (int r = 0; r < 4; ++r) {
      const int qrow = q0 + 4 * g + r;
      float sv[4];
#pragma unroll
      for (int kq = 0; kq < 4; ++kq) {
        sv[kq] = sf[kq][r] * alpha;
        if (maskt && (kv0 + kq * 16 + li > qrow)) sv[kq] = -3.0e38f;
      }
      float tm = fmaxf(fmaxf(sv[0], sv[1]), fmaxf(sv[2], sv[3]));
      tm = fmaxf(tm, __shfl_xor(tm, 1));
      tm = fmaxf(tm, __shfl_xor(tm, 2));
      tm = fmaxf(tm, __shfl_xor(tm, 4));
      tm = fmaxf(tm, __shfl_xor(tm, 8));
      const float mnew = fmaxf(m[r], tm);
      const float sc = exp2f(m[r] - mnew);
      float ps = 0.f;
#pragma unroll
      for (int kq = 0; kq < 4; ++kq) {
        const float p = exp2f(sv[kq] - mnew);
        ps += p;
        plds[wave][(4 * g + r) * 64 + kq * 16 + li] = (__bf16)p;
      }
      ps += __shfl_xor(ps, 1);
      ps += __shfl_xor(ps, 2);
      ps += __shfl_xor(ps, 4);
      ps += __shfl_xor(ps, 8);
      L[r] = L[r] * sc + ps;
      m[r] = mnew;
#pragma unroll
      for (int dt = 0; dt < 4; ++dt) o[dt][r] = o[dt][r] * sc;
    }
#pragma unroll
    for (int ks = 0; ks < 2; ++ks) {
      bf16x8 pa = *(const bf16x8*)&plds[wave][li * 64 + ks * 32 + g * 8];
#pragma unroll
      for (int dt = 0; dt < 4; ++dt) {
        bf16x8 vb =
            *(const bf16x8*)&Vp[(size_t)(dt * 16 + li) * S_ + kv0 + ks * 32 + g * 8];
        o[dt] = mfma16(pa, vb, o[dt]);
      }
    }
  }
  const int b = bh >> 4, h = bh & 15;
#pragma unroll
  for (int r = 0; r < 4; ++r) {
    const float inv = 1.0f / L[r];
    const int row = q0 + 4 * g + r;
#pragma unroll
    for (int dt = 0; dt < 4; ++dt)
      ao[(size_t)(b * S_ + row) * 1024 + h * 64 + dt * 16 + li] =
          (__bf16)(o[dt][r] * inv);
  }
}

// ---------------- launcher ----------------
extern "C" void kernel_launch(void* const* d_in, const int* in_sizes, int n_in,
                              void* d_out, int out_size, void* d_ws, size_t ws_size,
                              hipStream_t stream) {
  (void)in_sizes; (void)n_in; (void)out_size; (void)ws_size;
  const float* x = (const float*)d_in[0];
  // d_in[1] = mask (tril ones) -> causal handled analytically
  const float* W_dkv = (const float*)d_in[2];
  const float* b_dkv = (const float*)d_in[3];
  const float* W_dq = (const float*)d_in[4];
  const float* b_dq = (const float*)d_in[5];
  const float* W_uk = (const float*)d_in[6];
  const float* b_uk = (const float*)d_in[7];
  const float* W_uv = (const float*)d_in[8];
  const float* b_uv = (const float*)d_in[9];
  const float* W_uq = (const float*)d_in[10];
  const float* b_uq = (const float*)d_in[11];
  const float* W_qr = (const float*)d_in[12];
  const float* b_qr = (const float*)d_in[13];
  const float* W_kr = (const float*)d_in[14];
  const float* b_kr = (const float*)d_in[15];
  const float* W_o = (const float*)d_in[16];
  const float* b_o = (const float*)d_in[17];
  float* out = (float*)d_out;

  char* ws = (char*)d_ws;
  size_t off = 0;
  auto take = [&](size_t nbytes) -> char* {
    char* p = ws + off;
    off += (nbytes + 255) & ~(size_t)255;
    return p;
  };
  __bf16* xb = (__bf16*)take((size_t)8192 * 1024 * 2);
  __bf16* WdT = (__bf16*)take((size_t)384 * 1024 * 2);     // [Wdq|Wdkv|Wkr|pad]^T
  __bf16* WuqT = (__bf16*)take((size_t)1536 * 128 * 2);    // [Wuq|Wqr]^T
  __bf16* WukvT = (__bf16*)take((size_t)2048 * 128 * 2);   // [Wuk|Wuv]^T
  __bf16* WoT = (__bf16*)take((size_t)1024 * 1024 * 2);
  float* bias_d = (float*)take(384 * 4);
  float* bias_uq = (float*)take(1536 * 4);
  float* bias_ukv = (float*)take(2048 * 4);
  float* ropec = (float*)take((size_t)S_ * 16 * 4);
  float* ropes = (float*)take((size_t)S_ * 16 * 4);
  __bf16* cqkvr = (__bf16*)take((size_t)8192 * 384 * 2);   // [c_q|c_kv|k_r|pad]
  __bf16* qup = (__bf16*)take((size_t)8192 * 1536 * 2);    // [q_c|q_r]
  __bf16* kvup = (__bf16*)take((size_t)8192 * 2048 * 2);   // [k_c|v]
  __bf16* qt = (__bf16*)take((size_t)B_ * H_ * S_ * 96 * 2);
  __bf16* ktb = (__bf16*)take((size_t)B_ * H_ * S_ * 96 * 2);
  __bf16* vt = (__bf16*)take((size_t)B_ * H_ * 64 * S_ * 2);
  __bf16* aout = (__bf16*)take((size_t)8192 * 1024 * 2);

  // zero the padded rows of WdT (cols 288..383 of down-proj output)
  hipMemsetAsync(WdT + (size_t)288 * 1024, 0, (size_t)96 * 1024 * 2, stream);

  mla_cvt_x<<<4096, 256, 0, stream>>>(x, xb);
  mla_transpose<<<dim3(4, 32), dim3(32, 8), 0, stream>>>(W_dq, WdT, 1024, 128);
  mla_transpose<<<dim3(4, 32), dim3(32, 8), 0, stream>>>(W_dkv, WdT + (size_t)128 * 1024, 1024, 128);
  mla_transpose<<<dim3(1, 32), dim3(32, 8), 0, stream>>>(W_kr, WdT + (size_t)256 * 1024, 1024, 32);
  mla_transpose<<<dim3(32, 4), dim3(32, 8), 0, stream>>>(W_uq, WuqT, 128, 1024);
  mla_transpose<<<dim3(16, 4), dim3(32, 8), 0, stream>>>(W_qr, WuqT + (size_t)1024 * 128, 128, 512);
  mla_transpose<<<dim3(32, 4), dim3(32, 8), 0, stream>>>(W_uk, WukvT, 128, 1024);
  mla_transpose<<<dim3(32, 4), dim3(32, 8), 0, stream>>>(W_uv, WukvT + (size_t)1024 * 128, 128, 1024);
  mla_transpose<<<dim3(32, 32), dim3(32, 8), 0, stream>>>(W_o, WoT, 1024, 1024);
  mla_bias<<<8, 256, 0, stream>>>(b_dq, b_dkv, b_kr, b_uq, b_qr, b_uk, b_uv,
                                  bias_d, bias_uq, bias_ukv);
  mla_rope_tab<<<(S_ * 16) / 256, 256, 0, stream>>>(ropec, ropes);

  // down-proj: x(8192x1024) @ [Wdq|Wdkv|Wkr] -> cqkvr (8192x384)
  gemm_bf16k<false><<<dim3(3, 64), 256, 0, stream>>>(xb, 1024, WdT, 1024, bias_d,
                                                     cqkvr, 384, 1024);
  // up-proj q: c_q(8192x128) @ [Wuq|Wqr] -> qup (8192x1536)
  gemm_bf16k<false><<<dim3(12, 64), 256, 0, stream>>>(cqkvr, 384, WuqT, 128, bias_uq,
                                                      qup, 1536, 128);
  // up-proj kv: c_kv(8192x128) @ [Wuk|Wuv] -> kvup (8192x2048)
  gemm_bf16k<false><<<dim3(16, 64), 256, 0, stream>>>(cqkvr + 128, 384, WukvT, 128,
                                                      bias_ukv, kvup, 2048, 128);

  mla_build_qk<<<8192, 256, 0, stream>>>(qup, kvup, cqkvr, ropec, ropes, qt, ktb);
  mla_vtrans<<<dim3(32, 64), 256, 0, stream>>>(kvup, vt);
  mla_attn<<<dim3(32, 64), 256, 0, stream>>>(qt, ktb, vt, aout);

  // final: aout(8192x1024) @ W_o + b_o -> out f32
  gemm_bf16k<true><<<dim3(8, 64), 256, 0, stream>>>(aout, 1024, WoT, 1024, b_o, out,
                                                    1024, 1024);
}

// Round 2
// 436.240 us; speedup vs baseline: 1.8418x; 1.8418x over previous
//
#include <hip/hip_runtime.h>
#include <cstdint>
#include <cstddef>

#define S_ 2048
#define B_ 4
#define H_ 16

typedef __attribute__((ext_vector_type(8))) __bf16 bf16x8;
typedef __attribute__((ext_vector_type(4))) __bf16 bf16x4;
typedef __attribute__((ext_vector_type(4))) float f32x4;

__device__ __forceinline__ f32x4 mfma16(bf16x8 a, bf16x8 b, f32x4 c) {
  return __builtin_amdgcn_mfma_f32_16x16x32_bf16(a, b, c, 0, 0, 0);
}

// async global->LDS, 16B per lane. LDS base must be wave-uniform (HW writes
// base + lane*16); global src is per-lane.
__device__ __forceinline__ void gll16(const void* g, void* l) {
  __builtin_amdgcn_global_load_lds(
      (__attribute__((address_space(1))) void*)(uintptr_t)g,
      (__attribute__((address_space(3))) void*)(uint32_t)(uintptr_t)l,
      16, 0, 0);
}

// ---------------- prep kernels ----------------

__global__ __launch_bounds__(256) void mla_cvt_x(const float* __restrict__ x,
                                                 __bf16* __restrict__ xb) {
  const size_t i = ((size_t)blockIdx.x * 256 + threadIdx.x) * 8;
  float4 a = *(const float4*)&x[i];
  float4 b = *(const float4*)&x[i + 4];
  bf16x8 v;
  v[0] = (__bf16)a.x; v[1] = (__bf16)a.y; v[2] = (__bf16)a.z; v[3] = (__bf16)a.w;
  v[4] = (__bf16)b.x; v[5] = (__bf16)b.y; v[6] = (__bf16)b.z; v[7] = (__bf16)b.w;
  *(bf16x8*)&xb[i] = v;
}

// W (K x N, f32, row-major) -> WT (N x K, bf16, row-major)
__global__ void mla_transpose(const float* __restrict__ W, __bf16* __restrict__ WT,
                              int K, int N) {
  __shared__ float tile[32][33];
  const int n0 = blockIdx.x * 32, k0 = blockIdx.y * 32;
  const int tx = threadIdx.x, ty = threadIdx.y;
#pragma unroll
  for (int i = 0; i < 32; i += 8)
    tile[ty + i][tx] = W[(size_t)(k0 + ty + i) * N + n0 + tx];
  __syncthreads();
#pragma unroll
  for (int i = 0; i < 32; i += 8)
    WT[(size_t)(n0 + ty + i) * K + k0 + tx] = (__bf16)tile[tx][ty + i];
}

__global__ void mla_bias(const float* __restrict__ b_dq, const float* __restrict__ b_dkv,
                         const float* __restrict__ b_kr, const float* __restrict__ b_uq,
                         const float* __restrict__ b_qr, const float* __restrict__ b_uk,
                         const float* __restrict__ b_uv, float* __restrict__ bias_d,
                         float* __restrict__ bias_uq, float* __restrict__ bias_ukv) {
  const int t = blockIdx.x * 256 + threadIdx.x;
  if (t < 384)
    bias_d[t] = (t < 128) ? b_dq[t] : (t < 256) ? b_dkv[t - 128]
               : (t < 288) ? b_kr[t - 256] : 0.f;
  if (t < 1536) bias_uq[t] = (t < 1024) ? b_uq[t] : b_qr[t - 1024];
  if (t < 2048) bias_ukv[t] = (t < 1024) ? b_uk[t] : b_uv[t - 1024];
}

__global__ void mla_rope_tab(float* __restrict__ c, float* __restrict__ sn) {
  const int t = blockIdx.x * 256 + threadIdx.x;  // t < S_*16
  const int s = t >> 4, i = t & 15;
  // 10000^(-i/16) = exp2(-i * log2(10000)/16)
  const float inv = exp2f(-(float)i * (13.287712379549449f / 16.0f));
  const float ang = (float)s * inv;
  c[t] = cosf(ang);
  sn[t] = sinf(ang);
}

// ---------------- bf16 MFMA GEMM: C = A(MxK) * BT^T + bias ----------------
// A row-major (lda), BT is B transposed: N x K row-major (ldbt).
// 128x128 tile, BK=32, 4 waves in 2x2, 16 mfma(16x16x32)/k-step.
template <bool OUTF32>
__global__ __launch_bounds__(256) void gemm_bf16k(
    const __bf16* __restrict__ A, int lda, const __bf16* __restrict__ BT, int ldbt,
    const float* __restrict__ bias, void* __restrict__ Cout, int ldc, int K) {
  const int n0 = blockIdx.x * 128;
  const int m0 = blockIdx.y * 128;
  const int tid = threadIdx.x;
  const int wave = tid >> 6, lane = tid & 63;
  const int g = lane >> 4, li = lane & 15;
  const int wm = (wave >> 1) * 64, wn = (wave & 1) * 64;
  __shared__ __bf16 __attribute__((aligned(16))) ldsA[128 * 32];
  __shared__ __bf16 __attribute__((aligned(16))) ldsB[128 * 32];

  const f32x4 fz = {0.f, 0.f, 0.f, 0.f};
  f32x4 acc[4][4];
#pragma unroll
  for (int i = 0; i < 4; ++i)
#pragma unroll
    for (int j = 0; j < 4; ++j) acc[i][j] = fz;

  const int srow = lane >> 2;        // 0..15 within chunk
  const int skc = (lane & 3) * 8;    // k sub-offset (elems)

  for (int k0 = 0; k0 < K; k0 += 32) {
    __syncthreads();  // previous iteration's LDS reads done
#pragma unroll
    for (int c = 0; c < 4; ++c) {
      const int chunk = wave * 4 + c;           // 0..15
      const int r8 = (chunk & 7) * 16 + srow;   // tile row (A: m, B: n)
      if (chunk < 8)
        gll16(&A[(size_t)(m0 + r8) * lda + k0 + skc], &ldsA[(chunk & 7) * 512]);
      else
        gll16(&BT[(size_t)(n0 + r8) * ldbt + k0 + skc], &ldsB[(chunk & 7) * 512]);
    }
    __syncthreads();  // drains vmcnt -> staged data visible

    bf16x8 af[4], bfv[4];
#pragma unroll
    for (int mi = 0; mi < 4; ++mi)
      af[mi] = *(const bf16x8*)&ldsA[(wm + mi * 16 + li) * 32 + g * 8];
#pragma unroll
    for (int ni = 0; ni < 4; ++ni)
      bfv[ni] = *(const bf16x8*)&ldsB[(wn + ni * 16 + li) * 32 + g * 8];
#pragma unroll
    for (int mi = 0; mi < 4; ++mi)
#pragma unroll
      for (int ni = 0; ni < 4; ++ni)
        acc[mi][ni] = mfma16(af[mi], bfv[ni], acc[mi][ni]);
  }

#pragma unroll
  for (int ni = 0; ni < 4; ++ni) {
    const int col = n0 + wn + ni * 16 + li;
    const float bv = bias[col];
#pragma unroll
    for (int mi = 0; mi < 4; ++mi) {
#pragma unroll
      for (int r = 0; r < 4; ++r) {
        const int row = m0 + wm + mi * 16 + 4 * g + r;
        const float v = acc[mi][ni][r] + bv;
        if (OUTF32)
          ((float*)Cout)[(size_t)row * ldc + col] = v;
        else
          ((__bf16*)Cout)[(size_t)row * ldc + col] = (__bf16)v;
      }
    }
  }
}

// ---------------- glue: build q_t / k_t with RoPE ----------------
__global__ __launch_bounds__(256) void mla_build_qk(
    const __bf16* __restrict__ qup, const __bf16* __restrict__ kvup,
    const __bf16* __restrict__ cqkvr, const float* __restrict__ ropec,
    const float* __restrict__ ropes, __bf16* __restrict__ qt,
    __bf16* __restrict__ ktb) {
  const int bs = blockIdx.x;   // b*S + s
  const int b = bs >> 11;
  const int s = bs & 2047;
  __shared__ float krr[32];
  if (threadIdx.x < 16) {
    const int i = threadIdx.x;
    const float r = (float)cqkvr[(size_t)bs * 384 + 256 + 2 * i];
    const float im = (float)cqkvr[(size_t)bs * 384 + 256 + 2 * i + 1];
    const float c = ropec[s * 16 + i], sn = ropes[s * 16 + i];
    krr[2 * i] = r * c - im * sn;
    krr[2 * i + 1] = r * sn + im * c;
  }
  __syncthreads();
  for (int idx = threadIdx.x; idx < 1536; idx += 256) {
    const int h = idx / 96, d = idx - h * 96;
    const size_t orow = ((size_t)(b * H_ + h) * S_ + s) * 96;
    float qv, kv;
    if (d < 64) {
      qv = (float)qup[(size_t)bs * 1536 + h * 64 + d];
      kv = (float)kvup[(size_t)bs * 2048 + h * 64 + d];
    } else {
      const int i = (d - 64) >> 1;
      const float c = ropec[s * 16 + i], sn = ropes[s * 16 + i];
      const float r = (float)qup[(size_t)bs * 1536 + 1024 + h * 32 + 2 * i];
      const float im = (float)qup[(size_t)bs * 1536 + 1024 + h * 32 + 2 * i + 1];
      qv = (((d - 64) & 1) == 0) ? (r * c - im * sn) : (r * sn + im * c);
      kv = krr[d - 64];
    }
    qt[orow + d] = (__bf16)qv;
    ktb[orow + d] = (__bf16)kv;
  }
}

// ---------------- glue: V -> V^T (B,H,64,S) ----------------
__global__ __launch_bounds__(256) void mla_vtrans(const __bf16* __restrict__ kvup,
                                                  __bf16* __restrict__ vt) {
  const int s0 = blockIdx.x * 64;
  const int bh = blockIdx.y;
  const int b = bh >> 4, h = bh & 15;
  __shared__ __bf16 __attribute__((aligned(16))) tile[64][72];
  const int t = threadIdx.x;
  {
    const int r = t >> 2, c0 = (t & 3) * 16;
    const size_t src = (size_t)(b * S_ + s0 + r) * 2048 + 1024 + h * 64 + c0;
    bf16x8 u0 = *(const bf16x8*)&kvup[src];
    bf16x8 u1 = *(const bf16x8*)&kvup[src + 8];
    *(bf16x8*)&tile[r][c0] = u0;
    *(bf16x8*)&tile[r][c0 + 8] = u1;
  }
  __syncthreads();
  {
    const int d = t >> 2, sc0 = (t & 3) * 16;
    bf16x8 w0, w1;
#pragma unroll
    for (int e = 0; e < 8; ++e) {
      w0[e] = tile[sc0 + e][d];
      w1[e] = tile[sc0 + 8 + e][d];
    }
    const size_t dst = ((size_t)bh * 64 + d) * S_ + s0 + sc0;
    *(bf16x8*)&vt[dst] = w0;
    *(bf16x8*)&vt[dst + 8] = w1;
  }
}

// ---------------- causal flash attention v2 ----------------
// grid (S/64, B*H), 4 waves/block; wave owns 16 q-rows (swapped QK^T: lane's
// li = q-row). K/V tiles (64 kv) staged cooperatively into LDS via
// global_load_lds in [slice][kv][8] layout (contiguous-16B b128 reads),
// double-buffered 2-phase. P goes through a per-wave XOR-swizzled LDS tile.
__global__ __launch_bounds__(256) void mla_attn(const __bf16* __restrict__ qt,
                                                const __bf16* __restrict__ kt,
                                                const __bf16* __restrict__ vt,
                                                __bf16* __restrict__ ao) {
  const int qtile = (int)gridDim.x - 1 - blockIdx.x;  // heavy blocks first
  const int bh = blockIdx.y;
  const int wave = threadIdx.x >> 6, lane = threadIdx.x & 63;
  const int g = lane >> 4, li = lane & 15;
  const int q0w = qtile * 64 + wave * 16;
  const int wli = wave * 16 + li;  // q-row within 64-row block tile
  const float alpha = 1.4426950408889634f / sqrtf(96.0f);  // SCALE * log2(e)
  const __bf16* Q = qt + (size_t)bh * S_ * 96;
  const __bf16* Kp = kt + (size_t)bh * S_ * 96;
  const __bf16* Vp = vt + (size_t)bh * 64 * S_;

  // LDS: K tile 12 slices x 64 kv x 8 elems (12KB), V tile 8 slices (8KB), x2 buf
  __shared__ __bf16 __attribute__((aligned(16))) kbuf[2][12 * 512];
  __shared__ __bf16 __attribute__((aligned(16))) vbuf[2][8 * 512];
  __shared__ __bf16 __attribute__((aligned(16))) plds[4][1024];  // [wave][16q x 64kv]
  __shared__ float __attribute__((aligned(16))) scl[4][16];

  // Q fragments (B-operand: col=li=q, k=8g+e)
  bf16x8 qf[3];
#pragma unroll
  for (int kd = 0; kd < 3; ++kd)
    qf[kd] = *(const bf16x8*)&Q[(size_t)(q0w + li) * 96 + kd * 32 + g * 8];

  const f32x4 fz = {0.f, 0.f, 0.f, 0.f};
  f32x4 o[4];  // o[dt][r]: out[q=4g+r][dv=dt*16+li]
#pragma unroll
  for (int i = 0; i < 4; ++i) o[i] = fz;
  float m = -3.0e38f, L = 0.f;  // per-lane: q = li (replicated over g)

  char* pbase = (char*)&plds[wave][0];
  const int pxor = (li & 7) << 4;

  // stage tile t into buffer b: 20 chunks (12 K + 8 V), 5 per wave
  auto stage = [&](int t, int b) {
    const int kv0 = t * 64;
#pragma unroll
    for (int i = 0; i < 5; ++i) {
      const int c = wave + 4 * i;
      if (c < 12)
        gll16(&Kp[(size_t)(kv0 + lane) * 96 + c * 8], &kbuf[b][c * 512]);
      else
        gll16(&Vp[(size_t)lane * S_ + kv0 + (c - 12) * 8], &vbuf[b][(c - 12) * 512]);
    }
  };

  stage(0, 0);
  __syncthreads();

  int b = 0;
  for (int t = 0; t <= qtile; ++t) {
    if (t < qtile) stage(t + 1, b ^ 1);

    // QK^T (swapped): A = K frag (row=li -> kv=kq*16+li), B = Q frag
    f32x4 sf[4];
#pragma unroll
    for (int i = 0; i < 4; ++i) sf[i] = fz;
#pragma unroll
    for (int kq = 0; kq < 4; ++kq)
#pragma unroll
      for (int kd = 0; kd < 3; ++kd) {
        bf16x8 a = *(const bf16x8*)&kbuf[b][((kd * 4 + g) * 64 + kq * 16 + li) * 8];
        sf[kq] = mfma16(a, qf[kd], sf[kq]);
      }

    const bool maskt = (t == qtile);
    float sv[4][4];
#pragma unroll
    for (int kq = 0; kq < 4; ++kq)
#pragma unroll
      for (int r = 0; r < 4; ++r) {
        float v = sf[kq][r] * alpha;
        if (maskt && (kq * 16 + 4 * g + r > wli)) v = -3.0e38f;
        sv[kq][r] = v;
      }
    // row max: in-lane over 16, then cross-g
    float tm = sv[0][0];
#pragma unroll
    for (int kq = 0; kq < 4; ++kq)
#pragma unroll
      for (int r = 0; r < 4; ++r) tm = fmaxf(tm, sv[kq][r]);
    tm = fmaxf(tm, __shfl_xor(tm, 16));
    tm = fmaxf(tm, __shfl_xor(tm, 32));
    const float mnew = fmaxf(m, tm);

    float ps = 0.f;
#pragma unroll
    for (int kq = 0; kq < 4; ++kq) {
      const float p0 = exp2f(sv[kq][0] - mnew);
      const float p1 = exp2f(sv[kq][1] - mnew);
      const float p2 = exp2f(sv[kq][2] - mnew);
      const float p3 = exp2f(sv[kq][3] - mnew);
      ps += (p0 + p1) + (p2 + p3);
      bf16x4 pk;
      pk[0] = (__bf16)p0; pk[1] = (__bf16)p1; pk[2] = (__bf16)p2; pk[3] = (__bf16)p3;
      *(bf16x4*)(pbase + ((li * 128 + kq * 32 + g * 8) ^ pxor)) = pk;
    }
    ps += __shfl_xor(ps, 16);
    ps += __shfl_xor(ps, 32);
    const float sc = exp2f(m - mnew);
    L = L * sc + ps;
    m = mnew;
    if (g == 0) scl[wave][li] = sc;
    const float4 scv = *(const float4*)&scl[wave][4 * g];
    const f32x4 sc4 = {scv.x, scv.y, scv.z, scv.w};
#pragma unroll
    for (int dt = 0; dt < 4; ++dt) o[dt] *= sc4;

    // PV: A = P (row=li=q, k=kv), B = V (col=li=dv, k=kv)
#pragma unroll
    for (int ks = 0; ks < 2; ++ks) {
      bf16x8 pa = *(const bf16x8*)(pbase + ((li * 128 + ks * 64 + g * 16) ^ pxor));
#pragma unroll
      for (int dt = 0; dt < 4; ++dt) {
        bf16x8 vb = *(const bf16x8*)&vbuf[b][((ks * 4 + g) * 64 + dt * 16 + li) * 8];
        o[dt] = mfma16(pa, vb, o[dt]);
      }
    }

    __syncthreads();  // drains vmcnt (stage t+1 done) + LDS reads of buf b done
    b ^= 1;
  }

  if (g == 0) scl[wave][li] = L;
  const float4 Lv = *(const float4*)&scl[wave][4 * g];
  const int bb = bh >> 4, h = bh & 15;
  const float invL[4] = {1.f / Lv.x, 1.f / Lv.y, 1.f / Lv.z, 1.f / Lv.w};
#pragma unroll
  for (int r = 0; r < 4; ++r) {
    const int row = q0w + 4 * g + r;
#pragma unroll
    for (int dt = 0; dt < 4; ++dt)
      ao[(size_t)(bb * S_ + row) * 1024 + h * 64 + dt * 16 + li] =
          (__bf16)(o[dt][r] * invL[r]);
  }
}

// ---------------- launcher ----------------
extern "C" void kernel_launch(void* const* d_in, const int* in_sizes, int n_in,
                              void* d_out, int out_size, void* d_ws, size_t ws_size,
                              hipStream_t stream) {
  (void)in_sizes; (void)n_in; (void)out_size; (void)ws_size;
  const float* x = (const float*)d_in[0];
  // d_in[1] = mask (tril ones) -> causal handled analytically
  const float* W_dkv = (const float*)d_in[2];
  const float* b_dkv = (const float*)d_in[3];
  const float* W_dq = (const float*)d_in[4];
  const float* b_dq = (const float*)d_in[5];
  const float* W_uk = (const float*)d_in[6];
  const float* b_uk = (const float*)d_in[7];
  const float* W_uv = (const float*)d_in[8];
  const float* b_uv = (const float*)d_in[9];
  const float* W_uq = (const float*)d_in[10];
  const float* b_uq = (const float*)d_in[11];
  const float* W_qr = (const float*)d_in[12];
  const float* b_qr = (const float*)d_in[13];
  const float* W_kr = (const float*)d_in[14];
  const float* b_kr = (const float*)d_in[15];
  const float* W_o = (const float*)d_in[16];
  const float* b_o = (const float*)d_in[17];
  float* out = (float*)d_out;

  char* ws = (char*)d_ws;
  size_t off = 0;
  auto take = [&](size_t nbytes) -> char* {
    char* p = ws + off;
    off += (nbytes + 255) & ~(size_t)255;
    return p;
  };
  __bf16* xb = (__bf16*)take((size_t)8192 * 1024 * 2);
  __bf16* WdT = (__bf16*)take((size_t)384 * 1024 * 2);     // [Wdq|Wdkv|Wkr|pad]^T
  __bf16* WuqT = (__bf16*)take((size_t)1536 * 128 * 2);    // [Wuq|Wqr]^T
  __bf16* WukvT = (__bf16*)take((size_t)2048 * 128 * 2);   // [Wuk|Wuv]^T
  __bf16* WoT = (__bf16*)take((size_t)1024 * 1024 * 2);
  float* bias_d = (float*)take(384 * 4);
  float* bias_uq = (float*)take(1536 * 4);
  float* bias_ukv = (float*)take(2048 * 4);
  float* ropec = (float*)take((size_t)S_ * 16 * 4);
  float* ropes = (float*)take((size_t)S_ * 16 * 4);
  __bf16* cqkvr = (__bf16*)take((size_t)8192 * 384 * 2);   // [c_q|c_kv|k_r|pad]
  __bf16* qup = (__bf16*)take((size_t)8192 * 1536 * 2);    // [q_c|q_r]
  __bf16* kvup = (__bf16*)take((size_t)8192 * 2048 * 2);   // [k_c|v]
  __bf16* qt = (__bf16*)take((size_t)B_ * H_ * S_ * 96 * 2);
  __bf16* ktb = (__bf16*)take((size_t)B_ * H_ * S_ * 96 * 2);
  __bf16* vt = (__bf16*)take((size_t)B_ * H_ * 64 * S_ * 2);
  __bf16* aout = (__bf16*)take((size_t)8192 * 1024 * 2);

  // zero the padded rows of WdT (cols 288..383 of down-proj output)
  hipMemsetAsync(WdT + (size_t)288 * 1024, 0, (size_t)96 * 1024 * 2, stream);

  mla_cvt_x<<<4096, 256, 0, stream>>>(x, xb);
  mla_transpose<<<dim3(4, 32), dim3(32, 8), 0, stream>>>(W_dq, WdT, 1024, 128);
  mla_transpose<<<dim3(4, 32), dim3(32, 8), 0, stream>>>(W_dkv, WdT + (size_t)128 * 1024, 1024, 128);
  mla_transpose<<<dim3(1, 32), dim3(32, 8), 0, stream>>>(W_kr, WdT + (size_t)256 * 1024, 1024, 32);
  mla_transpose<<<dim3(32, 4), dim3(32, 8), 0, stream>>>(W_uq, WuqT, 128, 1024);
  mla_transpose<<<dim3(16, 4), dim3(32, 8), 0, stream>>>(W_qr, WuqT + (size_t)1024 * 128, 128, 512);
  mla_transpose<<<dim3(32, 4), dim3(32, 8), 0, stream>>>(W_uk, WukvT, 128, 1024);
  mla_transpose<<<dim3(32, 4), dim3(32, 8), 0, stream>>>(W_uv, WukvT + (size_t)1024 * 128, 128, 1024);
  mla_transpose<<<dim3(32, 32), dim3(32, 8), 0, stream>>>(W_o, WoT, 1024, 1024);
  mla_bias<<<8, 256, 0, stream>>>(b_dq, b_dkv, b_kr, b_uq, b_qr, b_uk, b_uv,
                                  bias_d, bias_uq, bias_ukv);
  mla_rope_tab<<<(S_ * 16) / 256, 256, 0, stream>>>(ropec, ropes);

  // down-proj: x(8192x1024) @ [Wdq|Wdkv|Wkr] -> cqkvr (8192x384)
  gemm_bf16k<false><<<dim3(3, 64), 256, 0, stream>>>(xb, 1024, WdT, 1024, bias_d,
                                                     cqkvr, 384, 1024);
  // up-proj q: c_q(8192x128) @ [Wuq|Wqr] -> qup (8192x1536)
  gemm_bf16k<false><<<dim3(12, 64), 256, 0, stream>>>(cqkvr, 384, WuqT, 128, bias_uq,
                                                      qup, 1536, 128);
  // up-proj kv: c_kv(8192x128) @ [Wuk|Wuv] -> kvup (8192x2048)
  gemm_bf16k<false><<<dim3(16, 64), 256, 0, stream>>>(cqkvr + 128, 384, WukvT, 128,
                                                      bias_ukv, kvup, 2048, 128);

  mla_build_qk<<<8192, 256, 0, stream>>>(qup, kvup, cqkvr, ropec, ropes, qt, ktb);
  mla_vtrans<<<dim3(32, 64), 256, 0, stream>>>(kvup, vt);
  mla_attn<<<dim3(32, 64), 256, 0, stream>>>(qt, ktb, vt, aout);

  // final: aout(8192x1024) @ W_o + b_o -> out f32
  gemm_bf16k<true><<<dim3(8, 64), 256, 0, stream>>>(aout, 1024, WoT, 1024, b_o, out,
                                                    1024, 1024);
}

// Round 4
// 399.416 us; speedup vs baseline: 2.0116x; 1.0922x over previous
//
#include <hip/hip_runtime.h>
#include <cstdint>
#include <cstddef>

#define S_ 2048
#define B_ 4
#define H_ 16

typedef __attribute__((ext_vector_type(8))) __bf16 bf16x8;
typedef __attribute__((ext_vector_type(4))) __bf16 bf16x4;
typedef __attribute__((ext_vector_type(4))) float f32x4;
typedef __attribute__((ext_vector_type(16))) float f32x16;

__device__ __forceinline__ f32x4 mfma16(bf16x8 a, bf16x8 b, f32x4 c) {
  return __builtin_amdgcn_mfma_f32_16x16x32_bf16(a, b, c, 0, 0, 0);
}
__device__ __forceinline__ f32x16 mfma32(bf16x8 a, bf16x8 b, f32x16 c) {
  return __builtin_amdgcn_mfma_f32_32x32x16_bf16(a, b, c, 0, 0, 0);
}

// async global->LDS, 16B per lane. LDS base must be wave-uniform (HW writes
// base + lane*16); global src is per-lane.
__device__ __forceinline__ void gll16(const void* g, void* l) {
  __builtin_amdgcn_global_load_lds(
      (__attribute__((address_space(1))) void*)(uintptr_t)g,
      (__attribute__((address_space(3))) void*)(uint32_t)(uintptr_t)l,
      16, 0, 0);
}

// v_cvt_pk_bf16_f32: packs (bf16(lo), bf16(hi)) into one dword (lo in bits 0-15)
__device__ __forceinline__ int cvtpk(float lo, float hi) {
  int r;
  asm("v_cvt_pk_bf16_f32 %0, %1, %2" : "=v"(r) : "v"(lo), "v"(hi));
  return r;
}

union PAU { int w[4]; bf16x8 v; };

// Build one 32x32x16 B-operand fragment of P^T (col=q=lane&31, k=8*hi+e)
// from 8 in-lane P values. Inputs: a0..a3 = P at kv base+{0..3}+4hi (low crow
// quad), b0..b3 = P at kv base+{8..11}+4hi (high crow quad).
// Required output on lane(hi): kv = base + 8*hi + {0..7}. The kv 4..7 /
// 12..15 values live on the partner half -> exchange via shfl_xor(32)
// (known-correct semantics; permlane32_swap orientation unverified -> not used).
__device__ __forceinline__ bf16x8 packPA(int hi, float a0, float a1, float a2,
                                         float a3, float b0, float b1, float b2,
                                         float b3) {
  const int Ylo = cvtpk(a0, a1);  // hi'=0: (kv0,kv1)   hi'=1: (kv4,kv5)
  const int Yhi = cvtpk(a2, a3);  // hi'=0: (kv2,kv3)   hi'=1: (kv6,kv7)
  const int Xlo = cvtpk(b0, b1);  // hi'=0: (kv8,kv9)   hi'=1: (kv12,kv13)
  const int Xhi = cvtpk(b2, b3);  // hi'=0: (kv10,kv11) hi'=1: (kv14,kv15)
  // hi=0 sends X*, receives partner's Y* ; hi=1 sends Y*, receives partner's X*
  const int t0 = __shfl_xor(hi ? Ylo : Xlo, 32);
  const int t1 = __shfl_xor(hi ? Yhi : Xhi, 32);
  PAU u;
  u.w[0] = hi ? t0 : Ylo;   // (kv0,kv1)   | (kv8,kv9)
  u.w[1] = hi ? t1 : Yhi;   // (kv2,kv3)   | (kv10,kv11)
  u.w[2] = hi ? Xlo : t0;   // (kv4,kv5)   | (kv12,kv13)
  u.w[3] = hi ? Xhi : t1;   // (kv6,kv7)   | (kv14,kv15)
  return u.v;
}

// ---------------- prep kernels ----------------

__global__ __launch_bounds__(256) void mla_cvt_x(const float* __restrict__ x,
                                                 __bf16* __restrict__ xb) {
  const size_t i = ((size_t)blockIdx.x * 256 + threadIdx.x) * 8;
  float4 a = *(const float4*)&x[i];
  float4 b = *(const float4*)&x[i + 4];
  bf16x8 v;
  v[0] = (__bf16)a.x; v[1] = (__bf16)a.y; v[2] = (__bf16)a.z; v[3] = (__bf16)a.w;
  v[4] = (__bf16)b.x; v[5] = (__bf16)b.y; v[6] = (__bf16)b.z; v[7] = (__bf16)b.w;
  *(bf16x8*)&xb[i] = v;
}

// W (K x N, f32, row-major) -> WT (N x K, bf16, row-major)
__global__ void mla_transpose(const float* __restrict__ W, __bf16* __restrict__ WT,
                              int K, int N) {
  __shared__ float tile[32][33];
  const int n0 = blockIdx.x * 32, k0 = blockIdx.y * 32;
  const int tx = threadIdx.x, ty = threadIdx.y;
#pragma unroll
  for (int i = 0; i < 32; i += 8)
    tile[ty + i][tx] = W[(size_t)(k0 + ty + i) * N + n0 + tx];
  __syncthreads();
#pragma unroll
  for (int i = 0; i < 32; i += 8)
    WT[(size_t)(n0 + ty + i) * K + k0 + tx] = (__bf16)tile[tx][ty + i];
}

__global__ void mla_bias(const float* __restrict__ b_dq, const float* __restrict__ b_dkv,
                         const float* __restrict__ b_kr, const float* __restrict__ b_uq,
                         const float* __restrict__ b_qr, const float* __restrict__ b_uk,
                         const float* __restrict__ b_uv, float* __restrict__ bias_d,
                         float* __restrict__ bias_uq, float* __restrict__ bias_ukv) {
  const int t = blockIdx.x * 256 + threadIdx.x;
  if (t < 384)
    bias_d[t] = (t < 128) ? b_dq[t] : (t < 256) ? b_dkv[t - 128]
               : (t < 288) ? b_kr[t - 256] : 0.f;
  if (t < 1536) bias_uq[t] = (t < 1024) ? b_uq[t] : b_qr[t - 1024];
  if (t < 2048) bias_ukv[t] = (t < 1024) ? b_uk[t] : b_uv[t - 1024];
}

__global__ void mla_rope_tab(float* __restrict__ c, float* __restrict__ sn) {
  const int t = blockIdx.x * 256 + threadIdx.x;  // t < S_*16
  const int s = t >> 4, i = t & 15;
  // 10000^(-i/16) = exp2(-i * log2(10000)/16)
  const float inv = exp2f(-(float)i * (13.287712379549449f / 16.0f));
  const float ang = (float)s * inv;
  c[t] = cosf(ang);
  sn[t] = sinf(ang);
}

// ---------------- bf16 MFMA GEMM: C = A(MxK) * BT^T + bias ----------------
template <bool OUTF32>
__global__ __launch_bounds__(256) void gemm_bf16k(
    const __bf16* __restrict__ A, int lda, const __bf16* __restrict__ BT, int ldbt,
    const float* __restrict__ bias, void* __restrict__ Cout, int ldc, int K) {
  const int n0 = blockIdx.x * 128;
  const int m0 = blockIdx.y * 128;
  const int tid = threadIdx.x;
  const int wave = tid >> 6, lane = tid & 63;
  const int g = lane >> 4, li = lane & 15;
  const int wm = (wave >> 1) * 64, wn = (wave & 1) * 64;
  __shared__ __bf16 __attribute__((aligned(16))) ldsA[128 * 32];
  __shared__ __bf16 __attribute__((aligned(16))) ldsB[128 * 32];

  const f32x4 fz = {0.f, 0.f, 0.f, 0.f};
  f32x4 acc[4][4];
#pragma unroll
  for (int i = 0; i < 4; ++i)
#pragma unroll
    for (int j = 0; j < 4; ++j) acc[i][j] = fz;

  const int srow = lane >> 2;
  const int skc = (lane & 3) * 8;

  for (int k0 = 0; k0 < K; k0 += 32) {
    __syncthreads();
#pragma unroll
    for (int c = 0; c < 4; ++c) {
      const int chunk = wave * 4 + c;
      const int r8 = (chunk & 7) * 16 + srow;
      if (chunk < 8)
        gll16(&A[(size_t)(m0 + r8) * lda + k0 + skc], &ldsA[(chunk & 7) * 512]);
      else
        gll16(&BT[(size_t)(n0 + r8) * ldbt + k0 + skc], &ldsB[(chunk & 7) * 512]);
    }
    __syncthreads();

    bf16x8 af[4], bfv[4];
#pragma unroll
    for (int mi = 0; mi < 4; ++mi)
      af[mi] = *(const bf16x8*)&ldsA[(wm + mi * 16 + li) * 32 + g * 8];
#pragma unroll
    for (int ni = 0; ni < 4; ++ni)
      bfv[ni] = *(const bf16x8*)&ldsB[(wn + ni * 16 + li) * 32 + g * 8];
#pragma unroll
    for (int mi = 0; mi < 4; ++mi)
#pragma unroll
      for (int ni = 0; ni < 4; ++ni)
        acc[mi][ni] = mfma16(af[mi], bfv[ni], acc[mi][ni]);
  }

#pragma unroll
  for (int ni = 0; ni < 4; ++ni) {
    const int col = n0 + wn + ni * 16 + li;
    const float bv = bias[col];
#pragma unroll
    for (int mi = 0; mi < 4; ++mi) {
#pragma unroll
      for (int r = 0; r < 4; ++r) {
        const int row = m0 + wm + mi * 16 + 4 * g + r;
        const float v = acc[mi][ni][r] + bv;
        if (OUTF32)
          ((float*)Cout)[(size_t)row * ldc + col] = v;
        else
          ((__bf16*)Cout)[(size_t)row * ldc + col] = (__bf16)v;
      }
    }
  }
}

// ---------------- glue: build q_t / k_t with RoPE ----------------
// q side is pre-scaled by SCALE*log2(e) so attention needs no per-score mul.
#define ALPHA_Q 0.14724394f
__global__ __launch_bounds__(256) void mla_build_qk(
    const __bf16* __restrict__ qup, const __bf16* __restrict__ kvup,
    const __bf16* __restrict__ cqkvr, const float* __restrict__ ropec,
    const float* __restrict__ ropes, __bf16* __restrict__ qt,
    __bf16* __restrict__ ktb) {
  const int bs = blockIdx.x;   // b*S + s
  const int b = bs >> 11;
  const int s = bs & 2047;
  __shared__ float krr[32];
  if (threadIdx.x < 16) {
    const int i = threadIdx.x;
    const float r = (float)cqkvr[(size_t)bs * 384 + 256 + 2 * i];
    const float im = (float)cqkvr[(size_t)bs * 384 + 256 + 2 * i + 1];
    const float c = ropec[s * 16 + i], sn = ropes[s * 16 + i];
    krr[2 * i] = r * c - im * sn;
    krr[2 * i + 1] = r * sn + im * c;
  }
  __syncthreads();
  for (int idx = threadIdx.x; idx < 1536; idx += 256) {
    const int h = idx / 96, d = idx - h * 96;
    const size_t orow = ((size_t)(b * H_ + h) * S_ + s) * 96;
    float qv, kv;
    if (d < 64) {
      qv = (float)qup[(size_t)bs * 1536 + h * 64 + d];
      kv = (float)kvup[(size_t)bs * 2048 + h * 64 + d];
    } else {
      const int i = (d - 64) >> 1;
      const float c = ropec[s * 16 + i], sn = ropes[s * 16 + i];
      const float r = (float)qup[(size_t)bs * 1536 + 1024 + h * 32 + 2 * i];
      const float im = (float)qup[(size_t)bs * 1536 + 1024 + h * 32 + 2 * i + 1];
      qv = (((d - 64) & 1) == 0) ? (r * c - im * sn) : (r * sn + im * c);
      kv = krr[d - 64];
    }
    qt[orow + d] = (__bf16)(qv * ALPHA_Q);
    ktb[orow + d] = (__bf16)kv;
  }
}

// ---------------- glue: V -> V^T (B,H,64,S) ----------------
__global__ __launch_bounds__(256) void mla_vtrans(const __bf16* __restrict__ kvup,
                                                  __bf16* __restrict__ vt) {
  const int s0 = blockIdx.x * 64;
  const int bh = blockIdx.y;
  const int b = bh >> 4, h = bh & 15;
  __shared__ __bf16 __attribute__((aligned(16))) tile[64][72];
  const int t = threadIdx.x;
  {
    const int r = t >> 2, c0 = (t & 3) * 16;
    const size_t src = (size_t)(b * S_ + s0 + r) * 2048 + 1024 + h * 64 + c0;
    bf16x8 u0 = *(const bf16x8*)&kvup[src];
    bf16x8 u1 = *(const bf16x8*)&kvup[src + 8];
    *(bf16x8*)&tile[r][c0] = u0;
    *(bf16x8*)&tile[r][c0 + 8] = u1;
  }
  __syncthreads();
  {
    const int d = t >> 2, sc0 = (t & 3) * 16;
    bf16x8 w0, w1;
#pragma unroll
    for (int e = 0; e < 8; ++e) {
      w0[e] = tile[sc0 + e][d];
      w1[e] = tile[sc0 + 8 + e][d];
    }
    const size_t dst = ((size_t)bh * 64 + d) * S_ + s0 + sc0;
    *(bf16x8*)&vt[dst] = w0;
    *(bf16x8*)&vt[dst + 8] = w1;
  }
}

// ---------------- causal flash attention v3 (32x32 MFMA) ----------------
// grid (S/128, B*H), 4 waves/block, wave owns 32 q-rows. KV tiles of 64,
// double-buffered LDS staging via global_load_lds.
// Swapped QK^T: mfma(K,Q) -> lane holds P[q=lane&31][kv=crow(r,hi)+32*kq].
// P -> PV B-fragments in-register (cvt_pk + shfl_xor(32) half-exchange).
// Swapped PV: mfma(V^T, P^T) -> out col=q=lane&31, so m/L/rescale are
// lane-uniform (no LDS broadcast).
__global__ __launch_bounds__(256, 3) void mla_attn(const __bf16* __restrict__ qt,
                                                   const __bf16* __restrict__ kt,
                                                   const __bf16* __restrict__ vt,
                                                   __bf16* __restrict__ ao) {
  const int qblk = (int)gridDim.x - 1 - blockIdx.x;  // heavy blocks first
  const int bh = blockIdx.y;
  const int wave = threadIdx.x >> 6, lane = threadIdx.x & 63;
  const int hi = lane >> 5, lq = lane & 31;
  const int q0w = qblk * 128 + wave * 32;
  const __bf16* Q = qt + (size_t)bh * S_ * 96;
  const __bf16* Kp = kt + (size_t)bh * S_ * 96;
  const __bf16* Vp = vt + (size_t)bh * 64 * S_;

  // K tile: 12 slices (d/8) x 64 kv x 8 ; V tile: 8 slices (kv/8) x 64 dv x 8
  __shared__ __bf16 __attribute__((aligned(16))) kbuf[2][12 * 512];
  __shared__ __bf16 __attribute__((aligned(16))) vbuf[2][8 * 512];

  // Q fragments: B-operand, col=lq, k = kd*16 + hi*8 + e  (pre-scaled by alpha)
  bf16x8 qf[6];
#pragma unroll
  for (int kd = 0; kd < 6; ++kd)
    qf[kd] = *(const bf16x8*)&Q[(size_t)(q0w + lq) * 96 + kd * 16 + hi * 8];

  const f32x16 fz16 = {0.f, 0.f, 0.f, 0.f, 0.f, 0.f, 0.f, 0.f,
                       0.f, 0.f, 0.f, 0.f, 0.f, 0.f, 0.f, 0.f};
  f32x16 o0 = fz16, o1 = fz16;  // out: col=lq=q, reg -> dv = dt*32 + crow(r,hi)
  float m = -3.0e38f, L = 0.f;

  const int tEnd = (q0w + 31) >> 6;        // last tile this wave computes
  const int tMax = qblk * 2 + 1;           // last tile the block stages

  auto stage = [&](int t, int bsel) {
    const int kv0 = t * 64;
#pragma unroll
    for (int i = 0; i < 5; ++i) {
      const int c = wave + 4 * i;
      if (c < 12)
        gll16(&Kp[(size_t)(kv0 + lane) * 96 + c * 8], &kbuf[bsel][c * 512]);
      else
        gll16(&Vp[(size_t)lane * S_ + kv0 + (c - 12) * 8], &vbuf[bsel][(c - 12) * 512]);
    }
  };

  stage(0, 0);
  __syncthreads();

  int bsel = 0;
  for (int t = 0; t <= tMax; ++t) {
    if (t < tMax) stage(t + 1, bsel ^ 1);
    if (t <= tEnd) {
      // QK^T: A = K (row=kv, k), B = Q. Two kv sub-tiles of 32.
      f32x16 s0 = fz16, s1 = fz16;
#pragma unroll
      for (int kd = 0; kd < 6; ++kd) {
        const int sl = kd * 2 + hi;
        bf16x8 a0 = *(const bf16x8*)&kbuf[bsel][(sl * 64 + lq) * 8];
        bf16x8 a1 = *(const bf16x8*)&kbuf[bsel][(sl * 64 + 32 + lq) * 8];
        s0 = mfma32(a0, qf[kd], s0);
        s1 = mfma32(a1, qf[kd], s1);
      }
      // mask diagonal tile: kv_g = t*64 + kq*32 + crow(r,hi) > q_g -> -inf
      if (t == tEnd) {
        const int qg = q0w + lq;
        const int kvb = t * 64 + 4 * hi;
#pragma unroll
        for (int r = 0; r < 16; ++r) {
          const int crow = (r & 3) + 8 * (r >> 2);
          if (kvb + crow > qg) s0[r] = -3.0e38f;
          if (kvb + 32 + crow > qg) s1[r] = -3.0e38f;
        }
      }
      // row max (32 in-lane + pair lane)
      float tm = s0[0];
#pragma unroll
      for (int r = 1; r < 16; ++r) tm = fmaxf(tm, s0[r]);
#pragma unroll
      for (int r = 0; r < 16; ++r) tm = fmaxf(tm, s1[r]);
      tm = fmaxf(tm, __shfl_xor(tm, 32));
      const float mnew = fmaxf(m, tm);
      // p = exp2(s - mnew), sum
      float p0[16], p1[16];
      float ps = 0.f;
#pragma unroll
      for (int r = 0; r < 16; ++r) {
        p0[r] = exp2f(s0[r] - mnew);
        p1[r] = exp2f(s1[r] - mnew);
        ps += p0[r] + p1[r];
      }
      ps += __shfl_xor(ps, 32);
      const float sc = exp2f(m - mnew);
      L = L * sc + ps;
      m = mnew;
      o0 *= sc;
      o1 *= sc;
      // P -> B-operand fragments (kv = ks*16 + hi*8 + e)
      bf16x8 pa[4];
      pa[0] = packPA(hi, p0[0], p0[1], p0[2], p0[3], p0[4], p0[5], p0[6], p0[7]);
      pa[1] = packPA(hi, p0[8], p0[9], p0[10], p0[11], p0[12], p0[13], p0[14], p0[15]);
      pa[2] = packPA(hi, p1[0], p1[1], p1[2], p1[3], p1[4], p1[5], p1[6], p1[7]);
      pa[3] = packPA(hi, p1[8], p1[9], p1[10], p1[11], p1[12], p1[13], p1[14], p1[15]);
      // PV (swapped): A = V^T (row=dv, k=kv), B = P^T (col=q, k=kv)
#pragma unroll
      for (int ks = 0; ks < 4; ++ks) {
        const int sl = ks * 2 + hi;
        bf16x8 v0 = *(const bf16x8*)&vbuf[bsel][(sl * 64 + lq) * 8];
        bf16x8 v1 = *(const bf16x8*)&vbuf[bsel][(sl * 64 + 32 + lq) * 8];
        o0 = mfma32(v0, pa[ks], o0);
        o1 = mfma32(v1, pa[ks], o1);
      }
    }
    __syncthreads();  // stage(t+1) complete + LDS reads of bsel done
    bsel ^= 1;
  }

  const float invL = 1.0f / L;
  const int bb = bh >> 4, h = bh & 15;
  __bf16* aorow = ao + (size_t)(bb * S_ + q0w + lq) * 1024 + h * 64;
#pragma unroll
  for (int rr = 0; rr < 4; ++rr) {
    bf16x4 w0, w1;
#pragma unroll
    for (int j = 0; j < 4; ++j) {
      w0[j] = (__bf16)(o0[4 * rr + j] * invL);
      w1[j] = (__bf16)(o1[4 * rr + j] * invL);
    }
    *(bf16x4*)&aorow[rr * 8 + 4 * hi] = w0;
    *(bf16x4*)&aorow[32 + rr * 8 + 4 * hi] = w1;
  }
}

// ---------------- launcher ----------------
extern "C" void kernel_launch(void* const* d_in, const int* in_sizes, int n_in,
                              void* d_out, int out_size, void* d_ws, size_t ws_size,
                              hipStream_t stream) {
  (void)in_sizes; (void)n_in; (void)out_size; (void)ws_size;
  const float* x = (const float*)d_in[0];
  // d_in[1] = mask (tril ones) -> causal handled analytically
  const float* W_dkv = (const float*)d_in[2];
  const float* b_dkv = (const float*)d_in[3];
  const float* W_dq = (const float*)d_in[4];
  const float* b_dq = (const float*)d_in[5];
  const float* W_uk = (const float*)d_in[6];
  const float* b_uk = (const float*)d_in[7];
  const float* W_uv = (const float*)d_in[8];
  const float* b_uv = (const float*)d_in[9];
  const float* W_uq = (const float*)d_in[10];
  const float* b_uq = (const float*)d_in[11];
  const float* W_qr = (const float*)d_in[12];
  const float* b_qr = (const float*)d_in[13];
  const float* W_kr = (const float*)d_in[14];
  const float* b_kr = (const float*)d_in[15];
  const float* W_o = (const float*)d_in[16];
  const float* b_o = (const float*)d_in[17];
  float* out = (float*)d_out;

  char* ws = (char*)d_ws;
  size_t off = 0;
  auto take = [&](size_t nbytes) -> char* {
    char* p = ws + off;
    off += (nbytes + 255) & ~(size_t)255;
    return p;
  };
  __bf16* xb = (__bf16*)take((size_t)8192 * 1024 * 2);
  __bf16* WdT = (__bf16*)take((size_t)384 * 1024 * 2);     // [Wdq|Wdkv|Wkr|pad]^T
  __bf16* WuqT = (__bf16*)take((size_t)1536 * 128 * 2);    // [Wuq|Wqr]^T
  __bf16* WukvT = (__bf16*)take((size_t)2048 * 128 * 2);   // [Wuk|Wuv]^T
  __bf16* WoT = (__bf16*)take((size_t)1024 * 1024 * 2);
  float* bias_d = (float*)take(384 * 4);
  float* bias_uq = (float*)take(1536 * 4);
  float* bias_ukv = (float*)take(2048 * 4);
  float* ropec = (float*)take((size_t)S_ * 16 * 4);
  float* ropes = (float*)take((size_t)S_ * 16 * 4);
  __bf16* cqkvr = (__bf16*)take((size_t)8192 * 384 * 2);   // [c_q|c_kv|k_r|pad]
  __bf16* qup = (__bf16*)take((size_t)8192 * 1536 * 2);    // [q_c|q_r]
  __bf16* kvup = (__bf16*)take((size_t)8192 * 2048 * 2);   // [k_c|v]
  __bf16* qt = (__bf16*)take((size_t)B_ * H_ * S_ * 96 * 2);
  __bf16* ktb = (__bf16*)take((size_t)B_ * H_ * S_ * 96 * 2);
  __bf16* vt = (__bf16*)take((size_t)B_ * H_ * 64 * S_ * 2);
  __bf16* aout = (__bf16*)take((size_t)8192 * 1024 * 2);

  // zero the padded rows of WdT (cols 288..383 of down-proj output)
  hipMemsetAsync(WdT + (size_t)288 * 1024, 0, (size_t)96 * 1024 * 2, stream);

  mla_cvt_x<<<4096, 256, 0, stream>>>(x, xb);
  mla_transpose<<<dim3(4, 32), dim3(32, 8), 0, stream>>>(W_dq, WdT, 1024, 128);
  mla_transpose<<<dim3(4, 32), dim3(32, 8), 0, stream>>>(W_dkv, WdT + (size_t)128 * 1024, 1024, 128);
  mla_transpose<<<dim3(1, 32), dim3(32, 8), 0, stream>>>(W_kr, WdT + (size_t)256 * 1024, 1024, 32);
  mla_transpose<<<dim3(32, 4), dim3(32, 8), 0, stream>>>(W_uq, WuqT, 128, 1024);
  mla_transpose<<<dim3(16, 4), dim3(32, 8), 0, stream>>>(W_qr, WuqT + (size_t)1024 * 128, 128, 512);
  mla_transpose<<<dim3(32, 4), dim3(32, 8), 0, stream>>>(W_uk, WukvT, 128, 1024);
  mla_transpose<<<dim3(32, 4), dim3(32, 8), 0, stream>>>(W_uv, WukvT + (size_t)1024 * 128, 128, 1024);
  mla_transpose<<<dim3(32, 32), dim3(32, 8), 0, stream>>>(W_o, WoT, 1024, 1024);
  mla_bias<<<8, 256, 0, stream>>>(b_dq, b_dkv, b_kr, b_uq, b_qr, b_uk, b_uv,
                                  bias_d, bias_uq, bias_ukv);
  mla_rope_tab<<<(S_ * 16) / 256, 256, 0, stream>>>(ropec, ropes);

  // down-proj: x(8192x1024) @ [Wdq|Wdkv|Wkr] -> cqkvr (8192x384)
  gemm_bf16k<false><<<dim3(3, 64), 256, 0, stream>>>(xb, 1024, WdT, 1024, bias_d,
                                                     cqkvr, 384, 1024);
  // up-proj q: c_q(8192x128) @ [Wuq|Wqr] -> qup (8192x1536)
  gemm_bf16k<false><<<dim3(12, 64), 256, 0, stream>>>(cqkvr, 384, WuqT, 128, bias_uq,
                                                      qup, 1536, 128);
  // up-proj kv: c_kv(8192x128) @ [Wuk|Wuv] -> kvup (8192x2048)
  gemm_bf16k<false><<<dim3(16, 64), 256, 0, stream>>>(cqkvr + 128, 384, WukvT, 128,
                                                      bias_ukv, kvup, 2048, 128);

  mla_build_qk<<<8192, 256, 0, stream>>>(qup, kvup, cqkvr, ropec, ropes, qt, ktb);
  mla_vtrans<<<dim3(32, 64), 256, 0, stream>>>(kvup, vt);
  mla_attn<<<dim3(16, 64), 256, 0, stream>>>(qt, ktb, vt, aout);

  // final: aout(8192x1024) @ W_o + b_o -> out f32
  gemm_bf16k<true><<<dim3(8, 64), 256, 0, stream>>>(aout, 1024, WoT, 1024, b_o, out,
                                                    1024, 1024);
}